// Round 12
// baseline (237.638 us; speedup 1.0000x reference)
//
#include <hip/hip_runtime.h>
#include <hip/hip_bf16.h>
#include <cstdint>

// Problem constants: B=2, H=16, L=2048, D=64
#define L_SEQ 2048
#define D_HEAD 64
#define N_HEADS 16
#define NBH 32   // B*H

typedef __attribute__((ext_vector_type(8))) __bf16 bf16x8;
typedef __attribute__((ext_vector_type(4))) __bf16 bf16x4;
typedef __attribute__((ext_vector_type(4))) float f32x4;

// ============================ prep kernels ============================

// Qb = bf16(Q * scale * log2e)  (so epilogue is exp2);  Kb = bf16(K)
__global__ __launch_bounds__(256) void prep_qk(const float* __restrict__ Q,
                                               const float* __restrict__ K,
                                               const float* __restrict__ scale_p,
                                               __bf16* __restrict__ Qb,
                                               __bf16* __restrict__ Kb) {
    const float c = scale_p[0] * 1.4426950408889634f;
    const size_t i = ((size_t)blockIdx.x * 256 + threadIdx.x) * 4;
    float4 q = *(const float4*)(Q + i);
    float4 k = *(const float4*)(K + i);
    __bf16 qo[4], ko[4];
    qo[0] = (__bf16)(q.x * c); qo[1] = (__bf16)(q.y * c);
    qo[2] = (__bf16)(q.z * c); qo[3] = (__bf16)(q.w * c);
    ko[0] = (__bf16)k.x; ko[1] = (__bf16)k.y; ko[2] = (__bf16)k.z; ko[3] = (__bf16)k.w;
    *(bf16x4*)(Qb + i) = *(bf16x4*)qo;
    *(bf16x4*)(Kb + i) = *(bf16x4*)ko;
}

// VbT[bh][d][k] = bf16(V[bh][k][d])  -- tiled transpose through LDS
__global__ __launch_bounds__(256) void prep_vt(const float* __restrict__ V,
                                               __bf16* __restrict__ VbT) {
    __shared__ __bf16 tile[64][72];
    const int bh = blockIdx.x >> 5;
    const int kt = blockIdx.x & 31;
    const int tid = threadIdx.x;
    const int r = tid >> 2;          // 0..63
    const int c = (tid & 3) * 16;    // 0,16,32,48
    const float* src = V + ((size_t)bh * L_SEQ + (size_t)kt * 64 + r) * D_HEAD + c;
    #pragma unroll
    for (int i = 0; i < 4; ++i) {
        float4 f = ((const float4*)src)[i];
        tile[r][c + i * 4 + 0] = (__bf16)f.x;
        tile[r][c + i * 4 + 1] = (__bf16)f.y;
        tile[r][c + i * 4 + 2] = (__bf16)f.z;
        tile[r][c + i * 4 + 3] = (__bf16)f.w;
    }
    __syncthreads();
    __bf16 out[16];
    #pragma unroll
    for (int j = 0; j < 16; ++j) out[j] = tile[c + j][r];   // [k][d] -> row d
    __bf16* dst = VbT + ((size_t)bh * D_HEAD + r) * L_SEQ + (size_t)kt * 64 + c;
    *(bf16x8*)dst       = *(bf16x8*)&out[0];
    *(bf16x8*)(dst + 8) = *(bf16x8*)&out[8];
}

// pack mask int32 -> bit per k: mp[row][kword], row in [B*L), 64 words/row
__global__ __launch_bounds__(256) void prep_mask(const int* __restrict__ mask,
                                                 unsigned int* __restrict__ mp) {
    const int wv   = blockIdx.x * 4 + (threadIdx.x >> 6);
    const int lane = threadIdx.x & 63;
    const int row  = wv >> 5;            // 0..4095
    const int k0   = (wv & 31) * 64;
    const int m = mask[(size_t)row * L_SEQ + k0 + lane];
    const unsigned long long b = __ballot(m != 0);
    if (lane < 2) mp[row * 64 + (k0 >> 5) + lane] = (unsigned int)(b >> (32 * lane));
}

// ============================ main kernel ============================
// Exact R8 champion (181 us) with ONE variable changed: attn/ctx stores are
// PLAIN cached stores instead of nontemporal. Rationale: rows are already
// 256B-contiguous (full 128B lines); the harness fill kernel reaches 6.8 TB/s
// with cached stores while our NT path measures ~4 TB/s effective. A/B test:
// if L2 dirty-line eviction beats the NT bypass, this wins; if K/V L2 slice
// gets thrashed, FETCH_SIZE balloons and it loses.
__global__ __launch_bounds__(256) void sdpa_main(
    const __bf16* __restrict__ Qb, const __bf16* __restrict__ Kb,
    const __bf16* __restrict__ VbT, const unsigned int* __restrict__ mp,
    float* __restrict__ ctx_out, float* __restrict__ attn_out)
{
    __shared__ __bf16 K_lds[64][72];
    __shared__ __bf16 V_lds[64][72];   // [d][k_local]
    __shared__ __bf16 P_lds[4][16][72];

    const int tid = threadIdx.x;
    const int w   = tid >> 6;     // wave 0..3
    const int l   = tid & 63;     // lane
    const int r15 = l & 15;
    const int g   = l >> 4;

    // bijective XCD swizzle: 1024 blocks -> 128 consecutive work-ids per XCD
    const int bid = blockIdx.x;
    const int wg  = (bid & 7) * 128 + (bid >> 3);
    const int bh  = wg >> 5;
    const int qt  = wg & 31;
    const int b   = bh >> 4;
    const int q0  = qt * 64;

    const __bf16* Kp = Kb  + (size_t)bh * L_SEQ * D_HEAD;
    const __bf16* Vp = VbT + (size_t)bh * D_HEAD * L_SEQ;

    // this lane's q row (swapped layout: q = col = r15)
    const int qq = q0 + w * 16 + r15;

    // Q fragments (bf16, pre-scaled) = MFMA B operand directly
    bf16x8 aq[2];
    {
        const __bf16* qrow = Qb + ((size_t)bh * L_SEQ + qq) * D_HEAD;
        aq[0] = *(const bf16x8*)(qrow + 8 * g);
        aq[1] = *(const bf16x8*)(qrow + 32 + 8 * g);
    }

    // staging decomposition: 64x64 bf16 tile, thread -> 16 consecutive bf16
    const int srow = tid >> 2;         // 0..63
    const int scol = (tid & 3) * 16;   // 0,16,32,48

    const unsigned int* mrow = mp + ((size_t)b * L_SEQ + qq) * 64;

    float lsum = 0.f;

    // ================= Pass 1: row sums (K staging pipelined) =================
    {
        bf16x8 ka = *(const bf16x8*)(Kp + (size_t)srow * D_HEAD + scol);
        bf16x8 kb = *(const bf16x8*)(Kp + (size_t)srow * D_HEAD + scol + 8);
        *(bf16x8*)&K_lds[srow][scol]     = ka;
        *(bf16x8*)&K_lds[srow][scol + 8] = kb;
        __syncthreads();

        for (int ch = 0; ch < 32; ++ch) {
            const int chn = (ch < 31) ? ch + 1 : ch;
            const __bf16* knp = Kp + (size_t)(chn * 64 + srow) * D_HEAD + scol;
            ka = *(const bf16x8*)knp;
            kb = *(const bf16x8*)(knp + 8);

            const uint2 mw = *(const uint2*)(mrow + 2 * ch);

            f32x4 acc[4] = {{0,0,0,0},{0,0,0,0},{0,0,0,0},{0,0,0,0}};
            #pragma unroll
            for (int t = 0; t < 4; ++t) {
                bf16x8 bk0 = *(const bf16x8*)&K_lds[t * 16 + r15][g * 8];
                bf16x8 bk1 = *(const bf16x8*)&K_lds[t * 16 + r15][32 + g * 8];
                acc[t] = __builtin_amdgcn_mfma_f32_16x16x32_bf16(bk0, aq[0], acc[t], 0, 0, 0);
                acc[t] = __builtin_amdgcn_mfma_f32_16x16x32_bf16(bk1, aq[1], acc[t], 0, 0, 0);
            }
            // acc[t][r] = S^T[k = 64ch + 16t + 4g + r][q = qq]
            #pragma unroll
            for (int t = 0; t < 4; ++t) {
                const unsigned int wsel = (t & 2) ? mw.y : mw.x;
                const unsigned int nib  = (wsel >> ((t & 1) * 16 + 4 * g)) & 0xFu;
                #pragma unroll
                for (int r = 0; r < 4; ++r) {
                    const float e = __builtin_exp2f(acc[t][r]);
                    lsum += ((nib >> r) & 1u) ? 0.f : e;
                }
            }

            __syncthreads();
            *(bf16x8*)&K_lds[srow][scol]     = ka;
            *(bf16x8*)&K_lds[srow][scol + 8] = kb;
            __syncthreads();
        }
    }

    // reduce across the 4 lanes sharing r15 (lanes l, l^16, l^32, l^48)
    lsum += __shfl_xor(lsum, 16);
    lsum += __shfl_xor(lsum, 32);
    const float inv = 1.0f / lsum;

    // ================= Pass 2: PV + full-line attn stores (pipelined) =========
    f32x4 ctx[4] = {{0,0,0,0},{0,0,0,0},{0,0,0,0},{0,0,0,0}};

    // attn store coords: lane stores cols sc..sc+3 of rows (4i + sr)
    const int sr = l >> 4;          // 0..3
    const int sc = (l & 15) * 4;    // 0..60
    float* abase = attn_out + ((size_t)bh * L_SEQ + q0 + w * 16) * L_SEQ;
    const int qrow_base = q0 + w * 16 + g * 4;   // ctx C rows (+r)

    {
        bf16x8 ka = *(const bf16x8*)(Kp + (size_t)srow * D_HEAD + scol);
        bf16x8 kb = *(const bf16x8*)(Kp + (size_t)srow * D_HEAD + scol + 8);
        bf16x8 va = *(const bf16x8*)(Vp + (size_t)srow * L_SEQ + scol);
        bf16x8 vb = *(const bf16x8*)(Vp + (size_t)srow * L_SEQ + scol + 8);
        __syncthreads();
        *(bf16x8*)&K_lds[srow][scol]     = ka;
        *(bf16x8*)&K_lds[srow][scol + 8] = kb;
        *(bf16x8*)&V_lds[srow][scol]     = va;
        *(bf16x8*)&V_lds[srow][scol + 8] = vb;
        __syncthreads();

        for (int ch = 0; ch < 32; ++ch) {
            const int k0 = ch * 64;
            const int chn = (ch < 31) ? ch + 1 : ch;
            const __bf16* knp = Kp + (size_t)(chn * 64 + srow) * D_HEAD + scol;
            const __bf16* vnp = Vp + (size_t)srow * L_SEQ + chn * 64 + scol;
            ka = *(const bf16x8*)knp;
            kb = *(const bf16x8*)(knp + 8);
            va = *(const bf16x8*)vnp;
            vb = *(const bf16x8*)(vnp + 8);

            const uint2 mw = *(const uint2*)(mrow + 2 * ch);

            f32x4 acc[4] = {{0,0,0,0},{0,0,0,0},{0,0,0,0},{0,0,0,0}};
            #pragma unroll
            for (int t = 0; t < 4; ++t) {
                bf16x8 bk0 = *(const bf16x8*)&K_lds[t * 16 + r15][g * 8];
                bf16x8 bk1 = *(const bf16x8*)&K_lds[t * 16 + r15][32 + g * 8];
                acc[t] = __builtin_amdgcn_mfma_f32_16x16x32_bf16(bk0, aq[0], acc[t], 0, 0, 0);
                acc[t] = __builtin_amdgcn_mfma_f32_16x16x32_bf16(bk1, aq[1], acc[t], 0, 0, 0);
            }
            // epilogue: p = exp2(s)*inv (masked); 4 consecutive k per b64 write
            #pragma unroll
            for (int t = 0; t < 4; ++t) {
                const unsigned int wsel = (t & 2) ? mw.y : mw.x;
                const unsigned int nib  = (wsel >> ((t & 1) * 16 + 4 * g)) & 0xFu;
                __bf16 pb[4];
                #pragma unroll
                for (int r = 0; r < 4; ++r) {
                    float e = __builtin_exp2f(acc[t][r]) * inv;
                    e = ((nib >> r) & 1u) ? 0.f : e;
                    pb[r] = (__bf16)e;
                }
                *(bf16x4*)&P_lds[w][r15][16 * t + 4 * g] = *(bf16x4*)pb;
            }
            // PV: wave-private P_lds; compiler inserts lgkm wait
            const bf16x8 pa0 = *(const bf16x8*)&P_lds[w][r15][8 * g];
            const bf16x8 pa1 = *(const bf16x8*)&P_lds[w][r15][32 + 8 * g];
            #pragma unroll
            for (int t2 = 0; t2 < 4; ++t2) {
                bf16x8 pv0 = *(const bf16x8*)&V_lds[t2 * 16 + r15][8 * g];
                bf16x8 pv1 = *(const bf16x8*)&V_lds[t2 * 16 + r15][32 + 8 * g];
                ctx[t2] = __builtin_amdgcn_mfma_f32_16x16x32_bf16(pa0, pv0, ctx[t2], 0, 0, 0);
                ctx[t2] = __builtin_amdgcn_mfma_f32_16x16x32_bf16(pa1, pv1, ctx[t2], 0, 0, 0);
            }
            // attn store from P_lds: 4 rows x 256B contiguous per instr.
            // PLAIN stores (the A/B variable): ride L2 dirty-line eviction.
            #pragma unroll
            for (int i = 0; i < 4; ++i) {
                const int row = 4 * i + sr;
                const uint2 raw = *(const uint2*)&P_lds[w][row][sc];
                f32x4 o;
                o[0] = __uint_as_float(raw.x << 16);
                o[1] = __uint_as_float(raw.x & 0xFFFF0000u);
                o[2] = __uint_as_float(raw.y << 16);
                o[3] = __uint_as_float(raw.y & 0xFFFF0000u);
                *(f32x4*)(abase + (size_t)row * L_SEQ + k0 + sc) = o;
            }

            __syncthreads();
            *(bf16x8*)&K_lds[srow][scol]     = ka;
            *(bf16x8*)&K_lds[srow][scol + 8] = kb;
            *(bf16x8*)&V_lds[srow][scol]     = va;
            *(bf16x8*)&V_lds[srow][scol + 8] = vb;
            __syncthreads();
        }
    }

    // ctx store: C row = qrow_base + r (q), col = 16t2 + r15 (d)
    #pragma unroll
    for (int t2 = 0; t2 < 4; ++t2) {
        #pragma unroll
        for (int r = 0; r < 4; ++r) {
            ctx_out[((size_t)bh * L_SEQ + qrow_base + r) * D_HEAD + t2 * 16 + r15] = ctx[t2][r];
        }
    }
}

// ===================== fallback (round-1 verified kernel) =====================
__global__ __launch_bounds__(256) void sdpa_fallback(
    const float* __restrict__ Q, const float* __restrict__ K,
    const float* __restrict__ V, const float* __restrict__ scale_p,
    const int* __restrict__ mask, float* __restrict__ ctx_out,
    float* __restrict__ attn_out)
{
    __shared__ __bf16 K_lds[64][72];
    __shared__ __bf16 V_lds[64][72];
    __shared__ __bf16 P_lds[4][16][72];

    const int tid = threadIdx.x;
    const int w   = tid >> 6;
    const int l   = tid & 63;
    const int r15 = l & 15;
    const int g   = l >> 4;

    const int qt = blockIdx.x & 31;
    const int bh = blockIdx.x >> 5;
    const int b  = bh >> 4;
    const int q0 = qt * 64;

    const float scale = *scale_p;
    const float* Qp = Q + (size_t)bh * L_SEQ * D_HEAD;
    const float* Kp = K + (size_t)bh * L_SEQ * D_HEAD;
    const float* Vp = V + (size_t)bh * L_SEQ * D_HEAD;
    const int*   Mp = mask + (size_t)b * L_SEQ * L_SEQ;

    bf16x8 aq[2];
    {
        const float* qrow = Qp + (size_t)(q0 + w * 16 + r15) * D_HEAD;
        #pragma unroll
        for (int kk = 0; kk < 2; ++kk) {
            const float* s = qrow + kk * 32 + g * 8;
            bf16x8 v;
            #pragma unroll
            for (int j = 0; j < 8; ++j) v[j] = (__bf16)s[j];
            aq[kk] = v;
        }
    }

    const int srow = tid >> 2;
    const int scol = (tid & 3) * 16;
    const int qrow_base = q0 + w * 16 + g * 4;

    float lsum[4] = {0.f, 0.f, 0.f, 0.f};

    for (int ch = 0; ch < 32; ++ch) {
        const int k0 = ch * 64;
        __syncthreads();
        {
            const float4* s4 = (const float4*)(Kp + (size_t)(k0 + srow) * D_HEAD + scol);
            __bf16 tmp[16];
            #pragma unroll
            for (int i = 0; i < 4; ++i) {
                float4 f = s4[i];
                tmp[i*4+0] = (__bf16)f.x; tmp[i*4+1] = (__bf16)f.y;
                tmp[i*4+2] = (__bf16)f.z; tmp[i*4+3] = (__bf16)f.w;
            }
            *(bf16x8*)&K_lds[srow][scol]     = *(bf16x8*)&tmp[0];
            *(bf16x8*)&K_lds[srow][scol + 8] = *(bf16x8*)&tmp[8];
        }
        __syncthreads();

        f32x4 acc[4] = {{0,0,0,0},{0,0,0,0},{0,0,0,0},{0,0,0,0}};
        #pragma unroll
        for (int t = 0; t < 4; ++t) {
            #pragma unroll
            for (int kk = 0; kk < 2; ++kk) {
                bf16x8 bk = *(const bf16x8*)&K_lds[t * 16 + r15][kk * 32 + g * 8];
                acc[t] = __builtin_amdgcn_mfma_f32_16x16x32_bf16(aq[kk], bk, acc[t], 0, 0, 0);
            }
        }
        #pragma unroll
        for (int t = 0; t < 4; ++t) {
            const int kcol = k0 + t * 16 + r15;
            #pragma unroll
            for (int r = 0; r < 4; ++r) {
                const int mk = Mp[(size_t)(qrow_base + r) * L_SEQ + kcol];
                const float s = acc[t][r] * scale;
                const float e = mk ? 0.0f : __expf(s);
                lsum[r] += e;
            }
        }
    }

    #pragma unroll
    for (int r = 0; r < 4; ++r) {
        float v = lsum[r];
        v += __shfl_xor(v, 1);
        v += __shfl_xor(v, 2);
        v += __shfl_xor(v, 4);
        v += __shfl_xor(v, 8);
        lsum[r] = 1.0f / v;
    }

    f32x4 ctx[4] = {{0,0,0,0},{0,0,0,0},{0,0,0,0},{0,0,0,0}};
    for (int ch = 0; ch < 32; ++ch) {
        const int k0 = ch * 64;
        __syncthreads();
        {
            const float4* s4 = (const float4*)(Kp + (size_t)(k0 + srow) * D_HEAD + scol);
            __bf16 tmp[16];
            #pragma unroll
            for (int i = 0; i < 4; ++i) {
                float4 f = s4[i];
                tmp[i*4+0] = (__bf16)f.x; tmp[i*4+1] = (__bf16)f.y;
                tmp[i*4+2] = (__bf16)f.z; tmp[i*4+3] = (__bf16)f.w;
            }
            *(bf16x8*)&K_lds[srow][scol]     = *(bf16x8*)&tmp[0];
            *(bf16x8*)&K_lds[srow][scol + 8] = *(bf16x8*)&tmp[8];
        }
        {
            const float4* s4 = (const float4*)(Vp + (size_t)(k0 + srow) * D_HEAD + scol);
            #pragma unroll
            for (int i = 0; i < 4; ++i) {
                float4 f = s4[i];
                V_lds[scol + i*4 + 0][srow] = (__bf16)f.x;
                V_lds[scol + i*4 + 1][srow] = (__bf16)f.y;
                V_lds[scol + i*4 + 2][srow] = (__bf16)f.z;
                V_lds[scol + i*4 + 3][srow] = (__bf16)f.w;
            }
        }
        __syncthreads();

        f32x4 acc[4] = {{0,0,0,0},{0,0,0,0},{0,0,0,0},{0,0,0,0}};
        #pragma unroll
        for (int t = 0; t < 4; ++t) {
            #pragma unroll
            for (int kk = 0; kk < 2; ++kk) {
                bf16x8 bk = *(const bf16x8*)&K_lds[t * 16 + r15][kk * 32 + g * 8];
                acc[t] = __builtin_amdgcn_mfma_f32_16x16x32_bf16(aq[kk], bk, acc[t], 0, 0, 0);
            }
        }
        #pragma unroll
        for (int t = 0; t < 4; ++t) {
            const int kcol = k0 + t * 16 + r15;
            #pragma unroll
            for (int r = 0; r < 4; ++r) {
                const int mk = Mp[(size_t)(qrow_base + r) * L_SEQ + kcol];
                const float s = acc[t][r] * scale;
                const float p = mk ? 0.0f : __expf(s) * lsum[r];
                __builtin_nontemporal_store(
                    p, &attn_out[((size_t)bh * L_SEQ + qrow_base + r) * L_SEQ + kcol]);
                P_lds[w][g * 4 + r][t * 16 + r15] = (__bf16)p;
            }
        }
        #pragma unroll
        for (int t2 = 0; t2 < 4; ++t2) {
            #pragma unroll
            for (int kk = 0; kk < 2; ++kk) {
                bf16x8 pa = *(const bf16x8*)&P_lds[w][r15][kk * 32 + g * 8];
                bf16x8 pv = *(const bf16x8*)&V_lds[t2 * 16 + r15][kk * 32 + g * 8];
                ctx[t2] = __builtin_amdgcn_mfma_f32_16x16x32_bf16(pa, pv, ctx[t2], 0, 0, 0);
            }
        }
    }

    #pragma unroll
    for (int t2 = 0; t2 < 4; ++t2) {
        #pragma unroll
        for (int r = 0; r < 4; ++r) {
            __builtin_nontemporal_store(
                ctx[t2][r],
                &ctx_out[((size_t)bh * L_SEQ + qrow_base + r) * D_HEAD + t2 * 16 + r15]);
        }
    }
}

// ============================ launcher ============================
extern "C" void kernel_launch(void* const* d_in, const int* in_sizes, int n_in,
                              void* d_out, int out_size, void* d_ws, size_t ws_size,
                              hipStream_t stream) {
    const float* Q     = (const float*)d_in[0];
    const float* K     = (const float*)d_in[1];
    const float* V     = (const float*)d_in[2];
    const float* scale = (const float*)d_in[3];
    const int*   mask  = (const int*)d_in[4];

    float* ctx_out  = (float*)d_out;
    float* attn_out = (float*)d_out + (size_t)NBH * L_SEQ * D_HEAD;

    const size_t bfbytes = (size_t)NBH * L_SEQ * D_HEAD * 2;  // 8,388,608
    const size_t need = 3 * bfbytes + (size_t)2 * L_SEQ * (L_SEQ / 32) * 4; // +1MB mask bits

    if (ws_size >= need) {
        __bf16* Qb  = (__bf16*)d_ws;
        __bf16* Kb  = Qb + (size_t)NBH * L_SEQ * D_HEAD;
        __bf16* VbT = Kb + (size_t)NBH * L_SEQ * D_HEAD;
        unsigned int* mp = (unsigned int*)((char*)d_ws + 3 * bfbytes);

        hipLaunchKernelGGL(prep_qk,   dim3(4096),  dim3(256), 0, stream, Q, K, scale, Qb, Kb);
        hipLaunchKernelGGL(prep_vt,   dim3(1024),  dim3(256), 0, stream, V, VbT);
        hipLaunchKernelGGL(prep_mask, dim3(32768), dim3(256), 0, stream, mask, mp);
        hipLaunchKernelGGL(sdpa_main, dim3(1024),  dim3(256), 0, stream,
                           Qb, Kb, VbT, mp, ctx_out, attn_out);
    } else {
        hipLaunchKernelGGL(sdpa_fallback, dim3(1024), dim3(256), 0, stream,
                           Q, K, V, scale, mask, ctx_out, attn_out);
    }
}

// Round 13
// 171.956 us; speedup vs baseline: 1.3820x; 1.3820x over previous
//
#include <hip/hip_runtime.h>
#include <hip/hip_bf16.h>
#include <cstdint>

// Problem constants: B=2, H=16, L=2048, D=64
#define L_SEQ 2048
#define D_HEAD 64
#define N_HEADS 16
#define NBH 32   // B*H

typedef __attribute__((ext_vector_type(8))) __bf16 bf16x8;
typedef __attribute__((ext_vector_type(4))) __bf16 bf16x4;
typedef __attribute__((ext_vector_type(4))) float f32x4;

// ============================ fused prep kernel ============================
// One launch instead of three: [0,4096) Q/K bf16 convert, [4096,5120) V
// transpose, [5120,13312) mask bit-pack. The three independent memory streams
// overlap instead of serializing across dispatches.
__global__ __launch_bounds__(256) void prep_fused(
    const float* __restrict__ Q, const float* __restrict__ K,
    const float* __restrict__ V, const float* __restrict__ scale_p,
    const int* __restrict__ mask,
    __bf16* __restrict__ Qb, __bf16* __restrict__ Kb,
    __bf16* __restrict__ VbT, unsigned int* __restrict__ mp)
{
    __shared__ __bf16 tile[64][72];
    const int bidx = blockIdx.x;

    if (bidx < 4096) {
        // ---- Qb = bf16(Q * scale * log2e); Kb = bf16(K) ----
        const float c = scale_p[0] * 1.4426950408889634f;
        const size_t i = ((size_t)bidx * 256 + threadIdx.x) * 4;
        float4 q = *(const float4*)(Q + i);
        float4 k = *(const float4*)(K + i);
        __bf16 qo[4], ko[4];
        qo[0] = (__bf16)(q.x * c); qo[1] = (__bf16)(q.y * c);
        qo[2] = (__bf16)(q.z * c); qo[3] = (__bf16)(q.w * c);
        ko[0] = (__bf16)k.x; ko[1] = (__bf16)k.y;
        ko[2] = (__bf16)k.z; ko[3] = (__bf16)k.w;
        *(bf16x4*)(Qb + i) = *(bf16x4*)qo;
        *(bf16x4*)(Kb + i) = *(bf16x4*)ko;
    } else if (bidx < 5120) {
        // ---- VbT[bh][d][k] = bf16(V[bh][k][d]) ----
        const int vb = bidx - 4096;
        const int bh = vb >> 5;
        const int kt = vb & 31;
        const int tid = threadIdx.x;
        const int r = tid >> 2;          // 0..63
        const int c = (tid & 3) * 16;    // 0,16,32,48
        const float* src = V + ((size_t)bh * L_SEQ + (size_t)kt * 64 + r) * D_HEAD + c;
        #pragma unroll
        for (int i = 0; i < 4; ++i) {
            float4 f = ((const float4*)src)[i];
            tile[r][c + i * 4 + 0] = (__bf16)f.x;
            tile[r][c + i * 4 + 1] = (__bf16)f.y;
            tile[r][c + i * 4 + 2] = (__bf16)f.z;
            tile[r][c + i * 4 + 3] = (__bf16)f.w;
        }
        __syncthreads();
        __bf16 out[16];
        #pragma unroll
        for (int j = 0; j < 16; ++j) out[j] = tile[c + j][r];   // [k][d] -> row d
        __bf16* dst = VbT + ((size_t)bh * D_HEAD + r) * L_SEQ + (size_t)kt * 64 + c;
        *(bf16x8*)dst       = *(bf16x8*)&out[0];
        *(bf16x8*)(dst + 8) = *(bf16x8*)&out[8];
    } else {
        // ---- mask int32 -> bit per k: mp[row][kword], 64 words/row ----
        // thread t owns ints [4t, 4t+4); 8-lane group covers one 32-bit word.
        const int t = (bidx - 5120) * 256 + threadIdx.x;   // 0 .. 2,097,151
        const int4 m4 = *(const int4*)(mask + 4 * (size_t)t);
        unsigned int nib = (m4.x != 0 ? 1u : 0u) | (m4.y != 0 ? 2u : 0u)
                         | (m4.z != 0 ? 4u : 0u) | (m4.w != 0 ? 8u : 0u);
        unsigned int word = nib << (4 * (threadIdx.x & 7));
        word |= __shfl_xor(word, 1);
        word |= __shfl_xor(word, 2);
        word |= __shfl_xor(word, 4);
        if ((threadIdx.x & 7) == 0) {
            const int k0  = 4 * t;             // global int index
            const int row = k0 >> 11;          // /2048
            const int col = (k0 & 2047) >> 5;  // /32
            mp[row * 64 + col] = word;
        }
    }
}

// ============================ main kernel ============================
// R8 champion, byte-identical (181 us): swapped QK^T (lane owns 4 consecutive
// k of one q-row -> P writes are b64, mask is 1 uint2/lane/chunk, lsum is 2
// shuffles); LDS-staged K/V with register prefetch; bf16 P bounce; full-line
// nontemporal attn stores (4 rows x 256B per instr) -- NT is load-bearing
// (R12 A/B: cached stores -31%); XCD-bijective block swizzle.
__global__ __launch_bounds__(256) void sdpa_main(
    const __bf16* __restrict__ Qb, const __bf16* __restrict__ Kb,
    const __bf16* __restrict__ VbT, const unsigned int* __restrict__ mp,
    float* __restrict__ ctx_out, float* __restrict__ attn_out)
{
    __shared__ __bf16 K_lds[64][72];
    __shared__ __bf16 V_lds[64][72];   // [d][k_local]
    __shared__ __bf16 P_lds[4][16][72];

    const int tid = threadIdx.x;
    const int w   = tid >> 6;     // wave 0..3
    const int l   = tid & 63;     // lane
    const int r15 = l & 15;
    const int g   = l >> 4;

    // bijective XCD swizzle: 1024 blocks -> 128 consecutive work-ids per XCD
    const int bid = blockIdx.x;
    const int wg  = (bid & 7) * 128 + (bid >> 3);
    const int bh  = wg >> 5;
    const int qt  = wg & 31;
    const int b   = bh >> 4;
    const int q0  = qt * 64;

    const __bf16* Kp = Kb  + (size_t)bh * L_SEQ * D_HEAD;
    const __bf16* Vp = VbT + (size_t)bh * D_HEAD * L_SEQ;

    // this lane's q row (swapped layout: q = col = r15)
    const int qq = q0 + w * 16 + r15;

    // Q fragments (bf16, pre-scaled) = MFMA B operand directly
    bf16x8 aq[2];
    {
        const __bf16* qrow = Qb + ((size_t)bh * L_SEQ + qq) * D_HEAD;
        aq[0] = *(const bf16x8*)(qrow + 8 * g);
        aq[1] = *(const bf16x8*)(qrow + 32 + 8 * g);
    }

    // staging decomposition: 64x64 bf16 tile, thread -> 16 consecutive bf16
    const int srow = tid >> 2;         // 0..63
    const int scol = (tid & 3) * 16;   // 0,16,32,48

    const unsigned int* mrow = mp + ((size_t)b * L_SEQ + qq) * 64;

    float lsum = 0.f;

    // ================= Pass 1: row sums (K staging pipelined) =================
    {
        bf16x8 ka = *(const bf16x8*)(Kp + (size_t)srow * D_HEAD + scol);
        bf16x8 kb = *(const bf16x8*)(Kp + (size_t)srow * D_HEAD + scol + 8);
        *(bf16x8*)&K_lds[srow][scol]     = ka;
        *(bf16x8*)&K_lds[srow][scol + 8] = kb;
        __syncthreads();

        for (int ch = 0; ch < 32; ++ch) {
            const int chn = (ch < 31) ? ch + 1 : ch;
            const __bf16* knp = Kp + (size_t)(chn * 64 + srow) * D_HEAD + scol;
            ka = *(const bf16x8*)knp;
            kb = *(const bf16x8*)(knp + 8);

            const uint2 mw = *(const uint2*)(mrow + 2 * ch);

            f32x4 acc[4] = {{0,0,0,0},{0,0,0,0},{0,0,0,0},{0,0,0,0}};
            #pragma unroll
            for (int t = 0; t < 4; ++t) {
                bf16x8 bk0 = *(const bf16x8*)&K_lds[t * 16 + r15][g * 8];
                bf16x8 bk1 = *(const bf16x8*)&K_lds[t * 16 + r15][32 + g * 8];
                acc[t] = __builtin_amdgcn_mfma_f32_16x16x32_bf16(bk0, aq[0], acc[t], 0, 0, 0);
                acc[t] = __builtin_amdgcn_mfma_f32_16x16x32_bf16(bk1, aq[1], acc[t], 0, 0, 0);
            }
            // acc[t][r] = S^T[k = 64ch + 16t + 4g + r][q = qq]
            #pragma unroll
            for (int t = 0; t < 4; ++t) {
                const unsigned int wsel = (t & 2) ? mw.y : mw.x;
                const unsigned int nib  = (wsel >> ((t & 1) * 16 + 4 * g)) & 0xFu;
                #pragma unroll
                for (int r = 0; r < 4; ++r) {
                    const float e = __builtin_exp2f(acc[t][r]);
                    lsum += ((nib >> r) & 1u) ? 0.f : e;
                }
            }

            __syncthreads();
            *(bf16x8*)&K_lds[srow][scol]     = ka;
            *(bf16x8*)&K_lds[srow][scol + 8] = kb;
            __syncthreads();
        }
    }

    // reduce across the 4 lanes sharing r15 (lanes l, l^16, l^32, l^48)
    lsum += __shfl_xor(lsum, 16);
    lsum += __shfl_xor(lsum, 32);
    const float inv = 1.0f / lsum;

    // ================= Pass 2: PV + full-line attn stores (pipelined) =========
    f32x4 ctx[4] = {{0,0,0,0},{0,0,0,0},{0,0,0,0},{0,0,0,0}};

    // attn store coords: lane stores cols sc..sc+3 of rows (4i + sr)
    const int sr = l >> 4;          // 0..3
    const int sc = (l & 15) * 4;    // 0..60
    float* abase = attn_out + ((size_t)bh * L_SEQ + q0 + w * 16) * L_SEQ;
    const int qrow_base = q0 + w * 16 + g * 4;   // ctx C rows (+r)

    {
        bf16x8 ka = *(const bf16x8*)(Kp + (size_t)srow * D_HEAD + scol);
        bf16x8 kb = *(const bf16x8*)(Kp + (size_t)srow * D_HEAD + scol + 8);
        bf16x8 va = *(const bf16x8*)(Vp + (size_t)srow * L_SEQ + scol);
        bf16x8 vb = *(const bf16x8*)(Vp + (size_t)srow * L_SEQ + scol + 8);
        __syncthreads();
        *(bf16x8*)&K_lds[srow][scol]     = ka;
        *(bf16x8*)&K_lds[srow][scol + 8] = kb;
        *(bf16x8*)&V_lds[srow][scol]     = va;
        *(bf16x8*)&V_lds[srow][scol + 8] = vb;
        __syncthreads();

        for (int ch = 0; ch < 32; ++ch) {
            const int k0 = ch * 64;
            const int chn = (ch < 31) ? ch + 1 : ch;
            const __bf16* knp = Kp + (size_t)(chn * 64 + srow) * D_HEAD + scol;
            const __bf16* vnp = Vp + (size_t)srow * L_SEQ + chn * 64 + scol;
            ka = *(const bf16x8*)knp;
            kb = *(const bf16x8*)(knp + 8);
            va = *(const bf16x8*)vnp;
            vb = *(const bf16x8*)(vnp + 8);

            const uint2 mw = *(const uint2*)(mrow + 2 * ch);

            f32x4 acc[4] = {{0,0,0,0},{0,0,0,0},{0,0,0,0},{0,0,0,0}};
            #pragma unroll
            for (int t = 0; t < 4; ++t) {
                bf16x8 bk0 = *(const bf16x8*)&K_lds[t * 16 + r15][g * 8];
                bf16x8 bk1 = *(const bf16x8*)&K_lds[t * 16 + r15][32 + g * 8];
                acc[t] = __builtin_amdgcn_mfma_f32_16x16x32_bf16(bk0, aq[0], acc[t], 0, 0, 0);
                acc[t] = __builtin_amdgcn_mfma_f32_16x16x32_bf16(bk1, aq[1], acc[t], 0, 0, 0);
            }
            // epilogue: p = exp2(s)*inv (masked); 4 consecutive k per b64 write
            #pragma unroll
            for (int t = 0; t < 4; ++t) {
                const unsigned int wsel = (t & 2) ? mw.y : mw.x;
                const unsigned int nib  = (wsel >> ((t & 1) * 16 + 4 * g)) & 0xFu;
                __bf16 pb[4];
                #pragma unroll
                for (int r = 0; r < 4; ++r) {
                    float e = __builtin_exp2f(acc[t][r]) * inv;
                    e = ((nib >> r) & 1u) ? 0.f : e;
                    pb[r] = (__bf16)e;
                }
                *(bf16x4*)&P_lds[w][r15][16 * t + 4 * g] = *(bf16x4*)pb;
            }
            // PV: wave-private P_lds; compiler inserts lgkm wait
            const bf16x8 pa0 = *(const bf16x8*)&P_lds[w][r15][8 * g];
            const bf16x8 pa1 = *(const bf16x8*)&P_lds[w][r15][32 + 8 * g];
            #pragma unroll
            for (int t2 = 0; t2 < 4; ++t2) {
                bf16x8 pv0 = *(const bf16x8*)&V_lds[t2 * 16 + r15][8 * g];
                bf16x8 pv1 = *(const bf16x8*)&V_lds[t2 * 16 + r15][32 + 8 * g];
                ctx[t2] = __builtin_amdgcn_mfma_f32_16x16x32_bf16(pa0, pv0, ctx[t2], 0, 0, 0);
                ctx[t2] = __builtin_amdgcn_mfma_f32_16x16x32_bf16(pa1, pv1, ctx[t2], 0, 0, 0);
            }
            // attn store from P_lds: 4 rows x 256B contiguous per instr (NT)
            #pragma unroll
            for (int i = 0; i < 4; ++i) {
                const int row = 4 * i + sr;
                const uint2 raw = *(const uint2*)&P_lds[w][row][sc];
                f32x4 o;
                o[0] = __uint_as_float(raw.x << 16);
                o[1] = __uint_as_float(raw.x & 0xFFFF0000u);
                o[2] = __uint_as_float(raw.y << 16);
                o[3] = __uint_as_float(raw.y & 0xFFFF0000u);
                __builtin_nontemporal_store(o, (f32x4*)(abase + (size_t)row * L_SEQ + k0 + sc));
            }

            __syncthreads();
            *(bf16x8*)&K_lds[srow][scol]     = ka;
            *(bf16x8*)&K_lds[srow][scol + 8] = kb;
            *(bf16x8*)&V_lds[srow][scol]     = va;
            *(bf16x8*)&V_lds[srow][scol + 8] = vb;
            __syncthreads();
        }
    }

    // ctx store: C row = qrow_base + r (q), col = 16t2 + r15 (d)
    #pragma unroll
    for (int t2 = 0; t2 < 4; ++t2) {
        #pragma unroll
        for (int r = 0; r < 4; ++r) {
            __builtin_nontemporal_store(
                ctx[t2][r],
                &ctx_out[((size_t)bh * L_SEQ + qrow_base + r) * D_HEAD + t2 * 16 + r15]);
        }
    }
}

// ===================== fallback (round-1 verified kernel) =====================
__global__ __launch_bounds__(256) void sdpa_fallback(
    const float* __restrict__ Q, const float* __restrict__ K,
    const float* __restrict__ V, const float* __restrict__ scale_p,
    const int* __restrict__ mask, float* __restrict__ ctx_out,
    float* __restrict__ attn_out)
{
    __shared__ __bf16 K_lds[64][72];
    __shared__ __bf16 V_lds[64][72];
    __shared__ __bf16 P_lds[4][16][72];

    const int tid = threadIdx.x;
    const int w   = tid >> 6;
    const int l   = tid & 63;
    const int r15 = l & 15;
    const int g   = l >> 4;

    const int qt = blockIdx.x & 31;
    const int bh = blockIdx.x >> 5;
    const int b  = bh >> 4;
    const int q0 = qt * 64;

    const float scale = *scale_p;
    const float* Qp = Q + (size_t)bh * L_SEQ * D_HEAD;
    const float* Kp = K + (size_t)bh * L_SEQ * D_HEAD;
    const float* Vp = V + (size_t)bh * L_SEQ * D_HEAD;
    const int*   Mp = mask + (size_t)b * L_SEQ * L_SEQ;

    bf16x8 aq[2];
    {
        const float* qrow = Qp + (size_t)(q0 + w * 16 + r15) * D_HEAD;
        #pragma unroll
        for (int kk = 0; kk < 2; ++kk) {
            const float* s = qrow + kk * 32 + g * 8;
            bf16x8 v;
            #pragma unroll
            for (int j = 0; j < 8; ++j) v[j] = (__bf16)s[j];
            aq[kk] = v;
        }
    }

    const int srow = tid >> 2;
    const int scol = (tid & 3) * 16;
    const int qrow_base = q0 + w * 16 + g * 4;

    float lsum[4] = {0.f, 0.f, 0.f, 0.f};

    for (int ch = 0; ch < 32; ++ch) {
        const int k0 = ch * 64;
        __syncthreads();
        {
            const float4* s4 = (const float4*)(Kp + (size_t)(k0 + srow) * D_HEAD + scol);
            __bf16 tmp[16];
            #pragma unroll
            for (int i = 0; i < 4; ++i) {
                float4 f = s4[i];
                tmp[i*4+0] = (__bf16)f.x; tmp[i*4+1] = (__bf16)f.y;
                tmp[i*4+2] = (__bf16)f.z; tmp[i*4+3] = (__bf16)f.w;
            }
            *(bf16x8*)&K_lds[srow][scol]     = *(bf16x8*)&tmp[0];
            *(bf16x8*)&K_lds[srow][scol + 8] = *(bf16x8*)&tmp[8];
        }
        __syncthreads();

        f32x4 acc[4] = {{0,0,0,0},{0,0,0,0},{0,0,0,0},{0,0,0,0}};
        #pragma unroll
        for (int t = 0; t < 4; ++t) {
            #pragma unroll
            for (int kk = 0; kk < 2; ++kk) {
                bf16x8 bk = *(const bf16x8*)&K_lds[t * 16 + r15][kk * 32 + g * 8];
                acc[t] = __builtin_amdgcn_mfma_f32_16x16x32_bf16(aq[kk], bk, acc[t], 0, 0, 0);
            }
        }
        #pragma unroll
        for (int t = 0; t < 4; ++t) {
            const int kcol = k0 + t * 16 + r15;
            #pragma unroll
            for (int r = 0; r < 4; ++r) {
                const int mk = Mp[(size_t)(qrow_base + r) * L_SEQ + kcol];
                const float s = acc[t][r] * scale;
                const float e = mk ? 0.0f : __expf(s);
                lsum[r] += e;
            }
        }
    }

    #pragma unroll
    for (int r = 0; r < 4; ++r) {
        float v = lsum[r];
        v += __shfl_xor(v, 1);
        v += __shfl_xor(v, 2);
        v += __shfl_xor(v, 4);
        v += __shfl_xor(v, 8);
        lsum[r] = 1.0f / v;
    }

    f32x4 ctx[4] = {{0,0,0,0},{0,0,0,0},{0,0,0,0},{0,0,0,0}};
    for (int ch = 0; ch < 32; ++ch) {
        const int k0 = ch * 64;
        __syncthreads();
        {
            const float4* s4 = (const float4*)(Kp + (size_t)(k0 + srow) * D_HEAD + scol);
            __bf16 tmp[16];
            #pragma unroll
            for (int i = 0; i < 4; ++i) {
                float4 f = s4[i];
                tmp[i*4+0] = (__bf16)f.x; tmp[i*4+1] = (__bf16)f.y;
                tmp[i*4+2] = (__bf16)f.z; tmp[i*4+3] = (__bf16)f.w;
            }
            *(bf16x8*)&K_lds[srow][scol]     = *(bf16x8*)&tmp[0];
            *(bf16x8*)&K_lds[srow][scol + 8] = *(bf16x8*)&tmp[8];
        }
        {
            const float4* s4 = (const float4*)(Vp + (size_t)(k0 + srow) * D_HEAD + scol);
            #pragma unroll
            for (int i = 0; i < 4; ++i) {
                float4 f = s4[i];
                V_lds[scol + i*4 + 0][srow] = (__bf16)f.x;
                V_lds[scol + i*4 + 1][srow] = (__bf16)f.y;
                V_lds[scol + i*4 + 2][srow] = (__bf16)f.z;
                V_lds[scol + i*4 + 3][srow] = (__bf16)f.w;
            }
        }
        __syncthreads();

        f32x4 acc[4] = {{0,0,0,0},{0,0,0,0},{0,0,0,0},{0,0,0,0}};
        #pragma unroll
        for (int t = 0; t < 4; ++t) {
            #pragma unroll
            for (int kk = 0; kk < 2; ++kk) {
                bf16x8 bk = *(const bf16x8*)&K_lds[t * 16 + r15][kk * 32 + g * 8];
                acc[t] = __builtin_amdgcn_mfma_f32_16x16x32_bf16(aq[kk], bk, acc[t], 0, 0, 0);
            }
        }
        #pragma unroll
        for (int t = 0; t < 4; ++t) {
            const int kcol = k0 + t * 16 + r15;
            #pragma unroll
            for (int r = 0; r < 4; ++r) {
                const int mk = Mp[(size_t)(qrow_base + r) * L_SEQ + kcol];
                const float s = acc[t][r] * scale;
                const float p = mk ? 0.0f : __expf(s) * lsum[r];
                __builtin_nontemporal_store(
                    p, &attn_out[((size_t)bh * L_SEQ + qrow_base + r) * L_SEQ + kcol]);
                P_lds[w][g * 4 + r][t * 16 + r15] = (__bf16)p;
            }
        }
        #pragma unroll
        for (int t2 = 0; t2 < 4; ++t2) {
            #pragma unroll
            for (int kk = 0; kk < 2; ++kk) {
                bf16x8 pa = *(const bf16x8*)&P_lds[w][r15][kk * 32 + g * 8];
                bf16x8 pv = *(const bf16x8*)&V_lds[t2 * 16 + r15][kk * 32 + g * 8];
                ctx[t2] = __builtin_amdgcn_mfma_f32_16x16x32_bf16(pa, pv, ctx[t2], 0, 0, 0);
            }
        }
    }

    #pragma unroll
    for (int t2 = 0; t2 < 4; ++t2) {
        #pragma unroll
        for (int r = 0; r < 4; ++r) {
            __builtin_nontemporal_store(
                ctx[t2][r],
                &ctx_out[((size_t)bh * L_SEQ + qrow_base + r) * D_HEAD + t2 * 16 + r15]);
        }
    }
}

// ============================ launcher ============================
extern "C" void kernel_launch(void* const* d_in, const int* in_sizes, int n_in,
                              void* d_out, int out_size, void* d_ws, size_t ws_size,
                              hipStream_t stream) {
    const float* Q     = (const float*)d_in[0];
    const float* K     = (const float*)d_in[1];
    const float* V     = (const float*)d_in[2];
    const float* scale = (const float*)d_in[3];
    const int*   mask  = (const int*)d_in[4];

    float* ctx_out  = (float*)d_out;
    float* attn_out = (float*)d_out + (size_t)NBH * L_SEQ * D_HEAD;

    const size_t bfbytes = (size_t)NBH * L_SEQ * D_HEAD * 2;  // 8,388,608
    const size_t need = 3 * bfbytes + (size_t)2 * L_SEQ * (L_SEQ / 32) * 4; // +1MB mask bits

    if (ws_size >= need) {
        __bf16* Qb  = (__bf16*)d_ws;
        __bf16* Kb  = Qb + (size_t)NBH * L_SEQ * D_HEAD;
        __bf16* VbT = Kb + (size_t)NBH * L_SEQ * D_HEAD;
        unsigned int* mp = (unsigned int*)((char*)d_ws + 3 * bfbytes);

        // fused prep: 4096 (Q/K cvt) + 1024 (V^T) + 8192 (mask pack) blocks
        hipLaunchKernelGGL(prep_fused, dim3(13312), dim3(256), 0, stream,
                           Q, K, V, scale, mask, Qb, Kb, VbT, mp);
        hipLaunchKernelGGL(sdpa_main,  dim3(1024),  dim3(256), 0, stream,
                           Qb, Kb, VbT, mp, ctx_out, attn_out);
    } else {
        hipLaunchKernelGGL(sdpa_fallback, dim3(1024), dim3(256), 0, stream,
                           Q, K, V, scale, mask, ctx_out, attn_out);
    }
}